// Round 10
// baseline (869.081 us; speedup 1.0000x reference)
//
#include <hip/hip_runtime.h>
#include <hip/hip_bf16.h>
#include <hip/hip_cooperative_groups.h>

namespace cg = cooperative_groups;

// Problem constants (from reference)
#define N_NODES 100000
#define N_EDGES 1600000
#define N_RELS  8
#define IN_F    64
#define HID_F   64
#define OUT_F   32
#define NSEG    (N_NODES * N_RELS)      // 800000 (node, rel) segments
#define SCAN_EPB 1024                   // elements per scan block (256 thr x 4)
#define SCAN_NB  ((NSEG + SCAN_EPB - 1) / SCAN_EPB)  // 782
#define PRE_BLOCKS 1024                 // cooperative grid (8 blocks/CU x 128 CU-worth; co-resident)

typedef __attribute__((ext_vector_type(8))) short short8;   // 8 bf16 = 4 VGPRs
typedef __attribute__((ext_vector_type(4))) float f32x4;

__device__ __forceinline__ float b2f(unsigned short u) {
    return __uint_as_float(((unsigned)u) << 16);
}
__device__ __forceinline__ unsigned short f2b(float f) {
    unsigned u = __float_as_uint(f);
    u += 0x7FFFu + ((u >> 16) & 1u);      // RNE
    return (unsigned short)(u >> 16);
}

#define PREP_W1 (576 * 64)
#define PREP_W2 (576 * 32)
#define PREP_CVT (N_NODES * 64 / 4)
#define PREP_TOT (PREP_W1 + PREP_W2 + PREP_CVT)

// ---------------------------------------------------------------------------
// 1) Fused cooperative preprocessing: one launch replaces
//    memset + hist + scanA + scanC + scat_prep (cnt/bsums stay L2-hot,
//    4 fewer launch overheads).
//    A: zero cnt; bf16 transposed weights; x -> bf16          grid.sync
//    B: histogram + rank (atomic-free scatter later)          grid.sync
//    C1: per-1024-chunk sums -> bsums                         grid.sync
//    C2: offs = exclusive scan (bsums prefix reduced inline)  grid.sync
//    D: scatter ssrc[offs[seg]+rank] = src*16+rel
// ---------------------------------------------------------------------------
__global__ void __launch_bounds__(256, 8) k_pre(
        const int* __restrict__ src, const int* __restrict__ dst,
        const int* __restrict__ et,
        int* __restrict__ cnt, int* __restrict__ rank, int* __restrict__ offs,
        int* __restrict__ bsums, int* __restrict__ ssrc,
        const float* __restrict__ W1, const float* __restrict__ root1,
        const float* __restrict__ W2, const float* __restrict__ root2,
        const float* __restrict__ x,
        ushort* __restrict__ Wt1b, ushort* __restrict__ Wt2b,
        ushort* __restrict__ xb) {
    cg::grid_group grid = cg::this_grid();
    __shared__ int red[256];
    __shared__ int ts[256];
    const int t = threadIdx.x;
    const int gtid = blockIdx.x * 256 + t;
    const int gsz = gridDim.x * 256;

    // ---- Phase A: zero cnt + weight/feature prep ----
    for (int i = gtid; i < NSEG; i += gsz) cnt[i] = 0;
    for (int j = gtid; j < PREP_TOT; j += gsz) {
        if (j < PREP_W1) {
            int o = j / 576, k = j - o * 576;
            float v = (k < 512) ? W1[k * 64 + o] : root1[(k - 512) * 64 + o];
            Wt1b[j] = f2b(v);
        } else if (j < PREP_W1 + PREP_W2) {
            int j2 = j - PREP_W1;
            int o = j2 / 576, k = j2 - o * 576;
            float v = (k < 512) ? W2[k * 32 + o] : root2[(k - 512) * 32 + o];
            Wt2b[j2] = f2b(v);
        } else {
            int j2 = j - PREP_W1 - PREP_W2;
            float4 v = *(const float4*)(x + (size_t)j2 * 4);
            ushort4 u;
            u.x = f2b(v.x); u.y = f2b(v.y); u.z = f2b(v.z); u.w = f2b(v.w);
            *(ushort4*)(xb + (size_t)j2 * 4) = u;
        }
    }
    grid.sync();

    // ---- Phase B: histogram + rank ----
    for (int e = gtid; e < N_EDGES; e += gsz) {
        int r = et[e];
        int seg = dst[e] * N_RELS + r;
        rank[e] = atomicAdd(&cnt[seg], 1);
    }
    grid.sync();

    // ---- Phase C1: per-chunk sums (blocks 0..SCAN_NB-1) ----
    if (blockIdx.x < SCAN_NB) {
        int base = blockIdx.x * SCAN_EPB + t * 4;
        int s = 0;
        #pragma unroll
        for (int j = 0; j < 4; ++j) {
            int idx = base + j;
            if (idx < NSEG) s += cnt[idx];
        }
        red[t] = s;
        __syncthreads();
        for (int st = 128; st > 0; st >>= 1) {
            if (t < st) red[t] += red[t + st];
            __syncthreads();
        }
        if (t == 0) bsums[blockIdx.x] = red[0];
    }
    grid.sync();

    // ---- Phase C2: exclusive offsets ----
    if (blockIdx.x < SCAN_NB) {
        int partial = 0;
        #pragma unroll
        for (int jj = 0; jj < 4; ++jj) {
            int j = t + jj * 256;
            if (j < SCAN_NB && j < (int)blockIdx.x) partial += bsums[j];
        }
        red[t] = partial;
        __syncthreads();
        for (int st = 128; st > 0; st >>= 1) {
            if (t < st) red[t] += red[t + st];
            __syncthreads();
        }
        const int base0 = red[0];

        int base = blockIdx.x * SCAN_EPB + t * 4;
        int v[4];
        int local = 0;
        #pragma unroll
        for (int j = 0; j < 4; ++j) {
            int idx = base + j;
            v[j] = (idx < NSEG) ? cnt[idx] : 0;
            local += v[j];
        }
        ts[t] = local;
        __syncthreads();
        for (int off = 1; off < 256; off <<= 1) {
            int xv = (t >= off) ? ts[t - off] : 0;
            __syncthreads();
            ts[t] += xv;
            __syncthreads();
        }
        int run = base0 + (ts[t] - local);
        #pragma unroll
        for (int j = 0; j < 4; ++j) {
            int idx = base + j;
            if (idx < NSEG) offs[idx] = run;
            run += v[j];
        }
    }
    grid.sync();

    // ---- Phase D: scatter (atomic-free, packed src*16+rel) ----
    for (int e = gtid; e < N_EDGES; e += gsz) {
        int r = et[e];
        int seg = dst[e] * N_RELS + r;
        ssrc[offs[seg] + rank[e]] = src[e] * 16 + r;
    }
}

// ---------------------------------------------------------------------------
// 2) Fused layer — EXACT R7 structure (best measured: 150 us, VGPR 36).
//    Block = 512 thr = 8 waves, 16 nodes. Wave w owns nodes {2w, 2w+1},
//    processed serially; per node: flat edge loop, 16 readlane broadcasts
//    (SGPR), 16 independent gathers in flight, scalar if-tree routing.
//    Phase 2: MFMA 16x16x32 bf16, 8 waves = NT n-tiles x S k-splits.
//    Phase 3: k-split partial C reduce via LDS, bias (+ReLU), store.
//    Floor: ~86 MB random L2-miss line fetches @ ~650 GB/s (concurrency-
//    limited). TLP > per-wave ILP here: VGPR-hungry interleaving regressed
//    (R6, R9); keep VGPR at 36.
// ---------------------------------------------------------------------------
template <int NOUT, bool RELU, typename OutT>
__global__ __launch_bounds__(512, 4) void k_layer(
        const ushort* __restrict__ xb, const int* __restrict__ offs,
        const int* __restrict__ cnt, const int* __restrict__ ssrc,
        const ushort* __restrict__ Wtb, const float* __restrict__ bias,
        OutT* __restrict__ out) {
    constexpr int NT = NOUT / 16;     // n-tiles
    constexpr int S  = 8 / NT;        // k-splits
    __shared__ __align__(16) ushort A_lds[16][584];   // 584 = 576 + 8 pad
    __shared__ f32x4 pc[6][64];                        // k-split partials

    const int tid = threadIdx.x;
    const int w = tid >> 6;
    const int f = tid & 63;
    const int node0 = blockIdx.x * 16;

    // ---- phase-2 wave assignment; preload first B-frag early ----
    const int t = w % NT, q = w / NT;
    constexpr int cbase = 18 / S, crem = 18 % S;
    const int cs = q * cbase + (q < crem ? q : crem);
    const int ce = cs + cbase + (q < crem ? 1 : 0);
    const int n0 = t * 16;
    const ushort* bptr = Wtb + (n0 + (f & 15)) * 576 + ((f >> 4) * 8);
    short8 bcur = *(const short8*)(bptr + cs * 32);

    // ---- phase-1 metadata: lanes 0..15 -> offs/cnt for both nodes' 8 rels --
    int ov = 0, cv = 0;
    if (f < 16) {
        ov = offs[(node0 + w * 2) * N_RELS + f];
        cv = cnt [(node0 + w * 2) * N_RELS + f];
    }

    for (int nd = 0; nd < 2; ++nd) {
        const int m = w * 2 + nd;
        const int node = node0 + m;
        const int s0 = __builtin_amdgcn_readlane(ov, nd * 8);
        const int ct = __builtin_amdgcn_readlane(ov, nd * 8 + 7)
                     + __builtin_amdgcn_readlane(cv, nd * 8 + 7) - s0;

        float a[8];
        #pragma unroll
        for (int r = 0; r < 8; ++r) a[r] = 0.0f;

        for (int cb = 0; cb < ct; cb += 64) {
            int n = ct - cb;
            if (n > 64) n = 64;
            int pk = 15;                          // pad: rel=15, src=0
            if (f < n) pk = ssrc[s0 + cb + f];
            for (int e = 0; e < n; e += 16) {
                int pv[16];
                float xv[16];
                #pragma unroll
                for (int i = 0; i < 16; ++i)
                    pv[i] = __builtin_amdgcn_readlane(pk, e + i);   // SGPR
                #pragma unroll
                for (int i = 0; i < 16; ++i)
                    xv[i] = b2f(xb[(size_t)(pv[i] >> 4) * 64 + f]); // 16 indep gathers
                #pragma unroll
                for (int i = 0; i < 16; ++i) {
                    const int rl = pv[i] & 15;                      // scalar
                    if (rl < 4) {
                        if (rl < 2) { if (rl == 0) a[0] += xv[i]; else a[1] += xv[i]; }
                        else        { if (rl == 2) a[2] += xv[i]; else a[3] += xv[i]; }
                    } else if (rl < 8) {
                        if (rl < 6) { if (rl == 4) a[4] += xv[i]; else a[5] += xv[i]; }
                        else        { if (rl == 6) a[6] += xv[i]; else a[7] += xv[i]; }
                    }   // rl >= 8: pad, drop
                }
            }
        }

        // normalize + bf16 -> LDS A rows; root row = own features
        #pragma unroll
        for (int r = 0; r < 8; ++r) {
            int c = __builtin_amdgcn_readlane(cv, nd * 8 + r);
            float inv = 1.0f / (float)(c > 0 ? c : 1);
            A_lds[m][r * 64 + f] = f2b(a[r] * inv);
        }
        A_lds[m][512 + f] = xb[node * 64 + f];
    }
    __syncthreads();

    // ---- Phase 2: MFMA over this wave's chunks (software-pipelined B) ----
    f32x4 acc = (f32x4){0.0f, 0.0f, 0.0f, 0.0f};
    const ushort* aptr = &A_lds[f & 15][(f >> 4) * 8];
    for (int c = cs; c < ce; ++c) {
        short8 bnext = bcur;
        if (c + 1 < ce) bnext = *(const short8*)(bptr + (c + 1) * 32);
        short8 af = *(const short8*)(aptr + c * 32);
        acc = __builtin_amdgcn_mfma_f32_16x16x32_bf16(af, bcur, acc, 0, 0, 0);
        bcur = bnext;
    }

    // ---- Phase 3: reduce k-splits, bias (+ReLU), store ----
    if (q > 0) pc[w - NT][f] = acc;
    __syncthreads();
    if (q == 0) {
        #pragma unroll
        for (int j = 1; j < S; ++j) {
            f32x4 p = pc[t + NT * (j - 1)][f];
            acc.x += p.x; acc.y += p.y; acc.z += p.z; acc.w += p.w;
        }
        const int col = f & 15;
        const float bs = bias[n0 + col];
        const int mrow = (f >> 4) * 4;   // C/D: row=(lane>>4)*4+reg, col=lane&15
        #pragma unroll
        for (int i = 0; i < 4; ++i) {
            float v = acc[i] + bs;
            if (RELU) v = fmaxf(v, 0.0f);
            size_t oi = (size_t)(node0 + mrow + i) * NOUT + n0 + col;
            if constexpr (sizeof(OutT) == 2) out[oi] = (OutT)f2b(v);
            else                             out[oi] = (OutT)v;
        }
    }
}

// ---------------------------------------------------------------------------
// Launch: 3 dispatches (k_pre cooperative, layer1, layer2)
// ---------------------------------------------------------------------------
extern "C" void kernel_launch(void* const* d_in, const int* in_sizes, int n_in,
                              void* d_out, int out_size, void* d_ws, size_t ws_size,
                              hipStream_t stream) {
    const float* x     = (const float*)d_in[0];
    const int*   ei    = (const int*)d_in[1];
    const int*   et    = (const int*)d_in[2];
    const float* W1    = (const float*)d_in[3];
    const float* root1 = (const float*)d_in[4];
    const float* b1    = (const float*)d_in[5];
    const float* W2    = (const float*)d_in[6];
    const float* root2 = (const float*)d_in[7];
    const float* b2    = (const float*)d_in[8];
    float* out = (float*)d_out;

    const int* src = ei;            // edge_index[0]
    const int* dst = ei + N_EDGES;  // edge_index[1]

    // Workspace layout (~38.5 MB):
    //   cnt 3.2M | offs 3.2M | bsums 4K | ssrc 6.4M | xb 12.8M |
    //   h1b 12.8M (rank overlaps its first 6.4M — dead before h1b written) |
    //   Wt1b 73.7K | Wt2b 36.9K
    char* ws = (char*)d_ws;
    int*    cnt   = (int*)(ws);
    int*    offs  = (int*)(ws + (size_t)NSEG * 4);
    int*    bsums = (int*)(ws + (size_t)NSEG * 8);
    int*    ssrc  = (int*)(ws + (size_t)NSEG * 8 + 4096);
    ushort* xb    = (ushort*)(ws + (size_t)NSEG * 8 + 4096 + (size_t)N_EDGES * 4);
    ushort* h1b   = (ushort*)((char*)xb + (size_t)N_NODES * 64 * 2);
    int*    rank  = (int*)h1b;   // overlap: rank dead after k_pre
    ushort* Wt1b  = (ushort*)((char*)h1b + (size_t)N_NODES * 64 * 2);
    ushort* Wt2b  = (ushort*)((char*)Wt1b + (size_t)PREP_W1 * 2);

    void* args[] = {
        (void*)&src, (void*)&dst, (void*)&et,
        (void*)&cnt, (void*)&rank, (void*)&offs, (void*)&bsums, (void*)&ssrc,
        (void*)&W1, (void*)&root1, (void*)&W2, (void*)&root2, (void*)&x,
        (void*)&Wt1b, (void*)&Wt2b, (void*)&xb
    };
    hipLaunchCooperativeKernel((void*)k_pre, dim3(PRE_BLOCKS), dim3(256),
                               args, 0, stream);

    // Layer 1: xb -> h1b (bf16, ReLU), NOUT=64
    k_layer<64, true, ushort><<<N_NODES / 16, 512, 0, stream>>>(
        xb, offs, cnt, ssrc, Wt1b, b1, h1b);
    // Layer 2: h1b -> out (fp32), NOUT=32
    k_layer<32, false, float><<<N_NODES / 16, 512, 0, stream>>>(
        h1b, offs, cnt, ssrc, Wt2b, b2, out);
}

// Round 11
// 438.199 us; speedup vs baseline: 1.9833x; 1.9833x over previous
//
#include <hip/hip_runtime.h>
#include <hip/hip_bf16.h>

// Problem constants (from reference)
#define N_NODES 100000
#define N_EDGES 1600000
#define N_RELS  8
#define IN_F    64
#define HID_F   64
#define OUT_F   32
#define NSEG    (N_NODES * N_RELS)      // 800000 (node, rel) segments
#define SCAN_EPB 1024                   // elements per scan block (256 thr x 4)
#define SCAN_NB  ((NSEG + SCAN_EPB - 1) / SCAN_EPB)  // 782

typedef __attribute__((ext_vector_type(8))) short short8;   // 8 bf16 = 4 VGPRs
typedef __attribute__((ext_vector_type(4))) float f32x4;

__device__ __forceinline__ float b2f(unsigned short u) {
    return __uint_as_float(((unsigned)u) << 16);
}
__device__ __forceinline__ unsigned short f2b(float f) {
    unsigned u = __float_as_uint(f);
    u += 0x7FFFu + ((u >> 16) & 1u);      // RNE
    return (unsigned short)(u >> 16);
}

#define PREP_W1 (576 * 64)
#define PREP_W2 (576 * 32)
#define PREP_CVT (N_NODES * 64 / 4)
#define PREP_TOT (PREP_W1 + PREP_W2 + PREP_CVT)

// ---------------------------------------------------------------------------
// 1) Histogram + rank (atomic-free scatter later), with prep work fused in:
//    hist threads are atomic-latency-bound, so the independent weight/feature
//    conversions ride along for free (grid-stride tail).
// ---------------------------------------------------------------------------
__global__ void k_hist(const int* __restrict__ dst, const int* __restrict__ et,
                       int* __restrict__ cnt, int* __restrict__ rank,
                       const float* __restrict__ W1, const float* __restrict__ root1,
                       const float* __restrict__ W2, const float* __restrict__ root2,
                       const float* __restrict__ x,
                       ushort* __restrict__ Wt1b, ushort* __restrict__ Wt2b,
                       ushort* __restrict__ xb) {
    const int e = blockIdx.x * 256 + threadIdx.x;
    const int gsz = gridDim.x * 256;
    // prep (independent; overlaps atomic latency)
    for (int j = e; j < PREP_TOT; j += gsz) {
        if (j < PREP_W1) {
            int o = j / 576, k = j - o * 576;
            float v = (k < 512) ? W1[k * 64 + o] : root1[(k - 512) * 64 + o];
            Wt1b[j] = f2b(v);
        } else if (j < PREP_W1 + PREP_W2) {
            int j2 = j - PREP_W1;
            int o = j2 / 576, k = j2 - o * 576;
            float v = (k < 512) ? W2[k * 32 + o] : root2[(k - 512) * 32 + o];
            Wt2b[j2] = f2b(v);
        } else {
            int j2 = j - PREP_W1 - PREP_W2;
            float4 v = *(const float4*)(x + (size_t)j2 * 4);
            ushort4 u;
            u.x = f2b(v.x); u.y = f2b(v.y); u.z = f2b(v.z); u.w = f2b(v.w);
            *(ushort4*)(xb + (size_t)j2 * 4) = u;
        }
    }
    if (e < N_EDGES) {
        int seg = dst[e] * N_RELS + et[e];
        rank[e] = atomicAdd(&cnt[seg], 1);
    }
}

// ---------------------------------------------------------------------------
// 2a) Scan pass A: per-block sums (1024 elems / block, 256 threads x 4)
// ---------------------------------------------------------------------------
__global__ void k_scanA(const int* __restrict__ cnt, int* __restrict__ bsums) {
    __shared__ int red[256];
    int t = threadIdx.x;
    int base = blockIdx.x * SCAN_EPB + t * 4;
    int s = 0;
    #pragma unroll
    for (int j = 0; j < 4; ++j) {
        int idx = base + j;
        if (idx < NSEG) s += cnt[idx];
    }
    red[t] = s;
    __syncthreads();
    for (int st = 128; st > 0; st >>= 1) {
        if (t < st) red[t] += red[t + st];
        __syncthreads();
    }
    if (t == 0) bsums[blockIdx.x] = red[0];
}

// ---------------------------------------------------------------------------
// 2b) Scan pass C (scanB inlined): block base = sum(bsums[j<blockIdx]),
//     then per-element exclusive offsets = base + local prefix
// ---------------------------------------------------------------------------
__global__ void k_scanC(const int* __restrict__ cnt, const int* __restrict__ bsums,
                        int* __restrict__ offs) {
    __shared__ int red[256];
    __shared__ int ts[256];
    int t = threadIdx.x;

    int partial = 0;
    #pragma unroll
    for (int jj = 0; jj < 4; ++jj) {
        int j = t + jj * 256;
        if (j < SCAN_NB && j < (int)blockIdx.x) partial += bsums[j];
    }
    red[t] = partial;
    __syncthreads();
    for (int st = 128; st > 0; st >>= 1) {
        if (t < st) red[t] += red[t + st];
        __syncthreads();
    }
    const int base0 = red[0];

    int base = blockIdx.x * SCAN_EPB + t * 4;
    int v[4];
    int local = 0;
    #pragma unroll
    for (int j = 0; j < 4; ++j) {
        int idx = base + j;
        v[j] = (idx < NSEG) ? cnt[idx] : 0;
        local += v[j];
    }
    ts[t] = local;
    __syncthreads();
    for (int off = 1; off < 256; off <<= 1) {
        int x = (t >= off) ? ts[t - off] : 0;
        __syncthreads();
        ts[t] += x;
        __syncthreads();
    }
    int run = base0 + (ts[t] - local);
    #pragma unroll
    for (int j = 0; j < 4; ++j) {
        int idx = base + j;
        if (idx < NSEG) offs[idx] = run;
        run += v[j];
    }
}

// ---------------------------------------------------------------------------
// 3) Pure scatter (atomic-free via rank): ssrc[offs[seg]+rank] = src*16+rel
// ---------------------------------------------------------------------------
__global__ void k_scat(const int* __restrict__ src, const int* __restrict__ dst,
                       const int* __restrict__ et, const int* __restrict__ offs,
                       const int* __restrict__ rank, int* __restrict__ ssrc) {
    int e = blockIdx.x * 256 + threadIdx.x;
    if (e < N_EDGES) {
        int r = et[e];
        int seg = dst[e] * N_RELS + r;
        ssrc[offs[seg] + rank[e]] = src[e] * 16 + r;
    }
}

// ---------------------------------------------------------------------------
// 4) Fused layer — EXACT R7 structure (best measured: 150 us, VGPR 36).
//    Block = 512 thr = 8 waves, 16 nodes. Wave w owns nodes {2w, 2w+1},
//    processed serially; per node: flat edge loop, 16 readlane broadcasts
//    (SGPR), 16 independent gathers in flight, scalar if-tree routing.
//    Phase 2: MFMA 16x16x32 bf16, 8 waves = NT n-tiles x S k-splits.
//    Phase 3: k-split partial C reduce via LDS, bias (+ReLU), store.
//    Floor: ~86 MB random L2-miss line fetches @ ~650 GB/s (concurrency-
//    limited). TLP > per-wave ILP here: VGPR-hungry interleaving regressed
//    (R6, R9); grid.sync fusion regressed (R10). Keep VGPR at 36.
// ---------------------------------------------------------------------------
template <int NOUT, bool RELU, typename OutT>
__global__ __launch_bounds__(512, 4) void k_layer(
        const ushort* __restrict__ xb, const int* __restrict__ offs,
        const int* __restrict__ cnt, const int* __restrict__ ssrc,
        const ushort* __restrict__ Wtb, const float* __restrict__ bias,
        OutT* __restrict__ out) {
    constexpr int NT = NOUT / 16;     // n-tiles
    constexpr int S  = 8 / NT;        // k-splits
    __shared__ __align__(16) ushort A_lds[16][584];   // 584 = 576 + 8 pad
    __shared__ f32x4 pc[6][64];                        // k-split partials

    const int tid = threadIdx.x;
    const int w = tid >> 6;
    const int f = tid & 63;
    const int node0 = blockIdx.x * 16;

    // ---- phase-2 wave assignment; preload first B-frag early ----
    const int t = w % NT, q = w / NT;
    constexpr int cbase = 18 / S, crem = 18 % S;
    const int cs = q * cbase + (q < crem ? q : crem);
    const int ce = cs + cbase + (q < crem ? 1 : 0);
    const int n0 = t * 16;
    const ushort* bptr = Wtb + (n0 + (f & 15)) * 576 + ((f >> 4) * 8);
    short8 bcur = *(const short8*)(bptr + cs * 32);

    // ---- phase-1 metadata: lanes 0..15 -> offs/cnt for both nodes' 8 rels --
    int ov = 0, cv = 0;
    if (f < 16) {
        ov = offs[(node0 + w * 2) * N_RELS + f];
        cv = cnt [(node0 + w * 2) * N_RELS + f];
    }

    for (int nd = 0; nd < 2; ++nd) {
        const int m = w * 2 + nd;
        const int node = node0 + m;
        const int s0 = __builtin_amdgcn_readlane(ov, nd * 8);
        const int ct = __builtin_amdgcn_readlane(ov, nd * 8 + 7)
                     + __builtin_amdgcn_readlane(cv, nd * 8 + 7) - s0;

        float a[8];
        #pragma unroll
        for (int r = 0; r < 8; ++r) a[r] = 0.0f;

        for (int cb = 0; cb < ct; cb += 64) {
            int n = ct - cb;
            if (n > 64) n = 64;
            int pk = 15;                          // pad: rel=15, src=0
            if (f < n) pk = ssrc[s0 + cb + f];
            for (int e = 0; e < n; e += 16) {
                int pv[16];
                float xv[16];
                #pragma unroll
                for (int i = 0; i < 16; ++i)
                    pv[i] = __builtin_amdgcn_readlane(pk, e + i);   // SGPR
                #pragma unroll
                for (int i = 0; i < 16; ++i)
                    xv[i] = b2f(xb[(size_t)(pv[i] >> 4) * 64 + f]); // 16 indep gathers
                #pragma unroll
                for (int i = 0; i < 16; ++i) {
                    const int rl = pv[i] & 15;                      // scalar
                    if (rl < 4) {
                        if (rl < 2) { if (rl == 0) a[0] += xv[i]; else a[1] += xv[i]; }
                        else        { if (rl == 2) a[2] += xv[i]; else a[3] += xv[i]; }
                    } else if (rl < 8) {
                        if (rl < 6) { if (rl == 4) a[4] += xv[i]; else a[5] += xv[i]; }
                        else        { if (rl == 6) a[6] += xv[i]; else a[7] += xv[i]; }
                    }   // rl >= 8: pad, drop
                }
            }
        }

        // normalize + bf16 -> LDS A rows; root row = own features
        #pragma unroll
        for (int r = 0; r < 8; ++r) {
            int c = __builtin_amdgcn_readlane(cv, nd * 8 + r);
            float inv = 1.0f / (float)(c > 0 ? c : 1);
            A_lds[m][r * 64 + f] = f2b(a[r] * inv);
        }
        A_lds[m][512 + f] = xb[node * 64 + f];
    }
    __syncthreads();

    // ---- Phase 2: MFMA over this wave's chunks (software-pipelined B) ----
    f32x4 acc = (f32x4){0.0f, 0.0f, 0.0f, 0.0f};
    const ushort* aptr = &A_lds[f & 15][(f >> 4) * 8];
    for (int c = cs; c < ce; ++c) {
        short8 bnext = bcur;
        if (c + 1 < ce) bnext = *(const short8*)(bptr + (c + 1) * 32);
        short8 af = *(const short8*)(aptr + c * 32);
        acc = __builtin_amdgcn_mfma_f32_16x16x32_bf16(af, bcur, acc, 0, 0, 0);
        bcur = bnext;
    }

    // ---- Phase 3: reduce k-splits, bias (+ReLU), store ----
    if (q > 0) pc[w - NT][f] = acc;
    __syncthreads();
    if (q == 0) {
        #pragma unroll
        for (int j = 1; j < S; ++j) {
            f32x4 p = pc[t + NT * (j - 1)][f];
            acc.x += p.x; acc.y += p.y; acc.z += p.z; acc.w += p.w;
        }
        const int col = f & 15;
        const float bs = bias[n0 + col];
        const int mrow = (f >> 4) * 4;   // C/D: row=(lane>>4)*4+reg, col=lane&15
        #pragma unroll
        for (int i = 0; i < 4; ++i) {
            float v = acc[i] + bs;
            if (RELU) v = fmaxf(v, 0.0f);
            size_t oi = (size_t)(node0 + mrow + i) * NOUT + n0 + col;
            if constexpr (sizeof(OutT) == 2) out[oi] = (OutT)f2b(v);
            else                             out[oi] = (OutT)v;
        }
    }
}

// ---------------------------------------------------------------------------
// Launch: 7 dispatches (memset, hist+prep, scanA, scanC, scat, layer1, layer2)
// ---------------------------------------------------------------------------
extern "C" void kernel_launch(void* const* d_in, const int* in_sizes, int n_in,
                              void* d_out, int out_size, void* d_ws, size_t ws_size,
                              hipStream_t stream) {
    const float* x     = (const float*)d_in[0];
    const int*   ei    = (const int*)d_in[1];
    const int*   et    = (const int*)d_in[2];
    const float* W1    = (const float*)d_in[3];
    const float* root1 = (const float*)d_in[4];
    const float* b1    = (const float*)d_in[5];
    const float* W2    = (const float*)d_in[6];
    const float* root2 = (const float*)d_in[7];
    const float* b2    = (const float*)d_in[8];
    float* out = (float*)d_out;

    const int* src = ei;            // edge_index[0]
    const int* dst = ei + N_EDGES;  // edge_index[1]

    // Workspace layout (~38.5 MB):
    //   cnt 3.2M | offs 3.2M | bsums 4K | ssrc 6.4M | xb 12.8M |
    //   h1b 12.8M (rank overlaps its first 6.4M — dead before h1b written) |
    //   Wt1b 73.7K | Wt2b 36.9K
    char* ws = (char*)d_ws;
    int*    cnt   = (int*)(ws);
    int*    offs  = (int*)(ws + (size_t)NSEG * 4);
    int*    bsums = (int*)(ws + (size_t)NSEG * 8);
    int*    ssrc  = (int*)(ws + (size_t)NSEG * 8 + 4096);
    ushort* xb    = (ushort*)(ws + (size_t)NSEG * 8 + 4096 + (size_t)N_EDGES * 4);
    ushort* h1b   = (ushort*)((char*)xb + (size_t)N_NODES * 64 * 2);
    int*    rank  = (int*)h1b;   // overlap: rank dead after k_scat
    ushort* Wt1b  = (ushort*)((char*)h1b + (size_t)N_NODES * 64 * 2);
    ushort* Wt2b  = (ushort*)((char*)Wt1b + (size_t)PREP_W1 * 2);

    hipMemsetAsync(cnt, 0, (size_t)NSEG * 4, stream);

    int eb = (N_EDGES + 255) / 256;
    k_hist<<<eb, 256, 0, stream>>>(dst, et, cnt, rank,
                                   W1, root1, W2, root2, x, Wt1b, Wt2b, xb);
    k_scanA<<<SCAN_NB, 256, 0, stream>>>(cnt, bsums);
    k_scanC<<<SCAN_NB, 256, 0, stream>>>(cnt, bsums, offs);
    k_scat<<<eb, 256, 0, stream>>>(src, dst, et, offs, rank, ssrc);

    // Layer 1: xb -> h1b (bf16, ReLU), NOUT=64
    k_layer<64, true, ushort><<<N_NODES / 16, 512, 0, stream>>>(
        xb, offs, cnt, ssrc, Wt1b, b1, h1b);
    // Layer 2: h1b -> out (fp32), NOUT=32
    k_layer<32, false, float><<<N_NODES / 16, 512, 0, stream>>>(
        h1b, offs, cnt, ssrc, Wt2b, b2, out);
}